// Round 1
// baseline (1400.504 us; speedup 1.0000x reference)
//
#include <hip/hip_runtime.h>
#include <hip/hip_bf16.h>

// VQ-VAE forward loss on MI355X.
// loss = 2.25 * mean((emb[argmin] - x)^2)
//      = 2.25/(N*D) * [ sum(x^2) + sum_n min_k(||e_k||^2 - 2 x_n.e_k) ]
// GEMM part (x . e_k) in bf16 MFMA 16x16x32; ||x||^2, ||e||^2 exact fp32.

#define NROWS (64 * 4096)   // 262144
#define DDIM  480
#define KCODES 512
#define BM    64            // rows per block
#define LDSS  488           // padded LDS row stride (bf16 elems); 976 B, 16B-aligned rows

typedef __bf16 bf16x8 __attribute__((ext_vector_type(8)));
typedef float  f32x4  __attribute__((ext_vector_type(4)));

__device__ __forceinline__ ushort f2bf(float v) {
    // round-to-nearest-even fp32 -> bf16 (inputs are finite normals)
    union { float f; unsigned u; } c; c.f = v;
    unsigned u = c.u;
    u += 0x7fffu + ((u >> 16) & 1u);
    return (ushort)(u >> 16);
}

// Convert codebook to bf16 in ws, compute ||e_k||^2 (fp32 exact), zero d_out.
__global__ void vq_setup(const float* __restrict__ e, ushort* __restrict__ ebf,
                         float* __restrict__ esq, float* __restrict__ out) {
    const int k = blockIdx.x;   // one code row per block (64 threads = 1 wave)
    const int t = threadIdx.x;
    if (k == 0 && t == 0) out[0] = 0.0f;
    float s = 0.0f;
    for (int d = t; d < DDIM; d += 64) {
        float v = e[k * DDIM + d];
        s += v * v;
        ebf[k * DDIM + d] = f2bf(v);
    }
    #pragma unroll
    for (int m = 32; m >= 1; m >>= 1) s += __shfl_xor(s, m, 64);
    if (t == 0) esq[k] = s;
}

__global__ __launch_bounds__(256) void vq_main(const float* __restrict__ x,
        const ushort* __restrict__ ebf, const float* __restrict__ esq,
        float* __restrict__ out) {
    __shared__ ushort xs[BM * LDSS];   // 62464 B -> 2 blocks/CU
    __shared__ float red[4 * BM];      // per-wave per-row mins
    __shared__ float redw[4];

    const int t    = threadIdx.x;
    const int wave = t >> 6;
    const int lane = t & 63;
    const int lrow = lane & 15;   // MFMA row/col lane index
    const int quad = lane >> 4;

    // ---- stage X tile (fp32 -> bf16 LDS), accumulate exact sum(x^2) ----
    const float4* xg = (const float4*)(x + (size_t)blockIdx.x * (BM * DDIM));
    float xsq = 0.0f;
    #pragma unroll
    for (int i = 0; i < 30; ++i) {        // 64*480/4 = 7680 float4 / 256 thr
        int f = i * 256 + t;
        float4 v = xg[f];
        xsq += v.x * v.x + v.y * v.y + v.z * v.z + v.w * v.w;
        int row = f / 120;                 // 120 float4 per row
        int col = f - row * 120;
        ushort4 b;
        b.x = f2bf(v.x); b.y = f2bf(v.y); b.z = f2bf(v.z); b.w = f2bf(v.w);
        *(ushort4*)(&xs[row * LDSS + col * 4]) = b;
    }
    __syncthreads();

    // ---- each wave: 64 rows x its 128-code slice ----
    const int code0 = wave * 128;
    float rmin[4][4];                      // [rowtile][reg] running min of (esq - 2*dot)
    #pragma unroll
    for (int r = 0; r < 4; ++r)
        #pragma unroll
        for (int j = 0; j < 4; ++j) rmin[r][j] = 1e30f;

    for (int g = 0; g < 2; ++g) {          // two groups of 64 codes
        const int cbase = code0 + g * 64;
        f32x4 acc[4][4];                   // [coltile][rowtile]
        #pragma unroll
        for (int c = 0; c < 4; ++c)
            #pragma unroll
            for (int r = 0; r < 4; ++r) acc[c][r] = (f32x4){0.f, 0.f, 0.f, 0.f};

        #pragma unroll
        for (int dk = 0; dk < 15; ++dk) {  // D = 15 * 32
            bf16x8 bfr[4];
            #pragma unroll
            for (int c = 0; c < 4; ++c)
                bfr[c] = *(const bf16x8*)(ebf +
                    (size_t)(cbase + c * 16 + lrow) * DDIM + dk * 32 + quad * 8);
            #pragma unroll
            for (int r = 0; r < 4; ++r) {
                bf16x8 afr = *(const bf16x8*)(&xs[(r * 16 + lrow) * LDSS + dk * 32 + quad * 8]);
                #pragma unroll
                for (int c = 0; c < 4; ++c)
                    acc[c][r] = __builtin_amdgcn_mfma_f32_16x16x32_bf16(afr, bfr[c], acc[c][r], 0, 0, 0);
            }
        }
        // fold: dist_part = esq[col] - 2*dot ; acc[c][r][j] is (row=quad*4+j, col=lrow)
        #pragma unroll
        for (int c = 0; c < 4; ++c) {
            float es = esq[cbase + c * 16 + lrow];
            #pragma unroll
            for (int r = 0; r < 4; ++r)
                #pragma unroll
                for (int j = 0; j < 4; ++j)
                    rmin[r][j] = fminf(rmin[r][j], es - 2.0f * acc[c][r][j]);
        }
    }

    // ---- cross-lane min over the 16 col lanes (bits 0..3, stays in quad) ----
    #pragma unroll
    for (int r = 0; r < 4; ++r)
        #pragma unroll
        for (int j = 0; j < 4; ++j) {
            float v = rmin[r][j];
            v = fminf(v, __shfl_xor(v, 1, 64));
            v = fminf(v, __shfl_xor(v, 2, 64));
            v = fminf(v, __shfl_xor(v, 4, 64));
            v = fminf(v, __shfl_xor(v, 8, 64));
            if (lrow == 0) red[wave * 64 + r * 16 + quad * 4 + j] = v;
        }
    __syncthreads();

    // ---- combine: min across 4 waves per row, + sum(x^2), block reduce ----
    float val = xsq;
    if (t < 64)
        val += fminf(fminf(red[t], red[64 + t]), fminf(red[128 + t], red[192 + t]));
    #pragma unroll
    for (int m = 32; m >= 1; m >>= 1) val += __shfl_xor(val, m, 64);
    if (lane == 0) redw[wave] = val;
    __syncthreads();
    if (t == 0) {
        const float SCALE = 2.25f / ((float)NROWS * (float)DDIM);
        atomicAdd(out, (redw[0] + redw[1] + redw[2] + redw[3]) * SCALE);
    }
}

extern "C" void kernel_launch(void* const* d_in, const int* in_sizes, int n_in,
                              void* d_out, int out_size, void* d_ws, size_t ws_size,
                              hipStream_t stream) {
    (void)in_sizes; (void)n_in; (void)out_size; (void)ws_size;
    const float* x = (const float*)d_in[0];   // [262144, 480] fp32
    const float* e = (const float*)d_in[1];   // [512, 480] fp32
    float* out = (float*)d_out;               // scalar fp32
    ushort* ebf = (ushort*)d_ws;                              // 512*480*2 = 491520 B
    float*  esq = (float*)((char*)d_ws + KCODES * DDIM * 2);  // 512*4 B

    vq_setup<<<KCODES, 64, 0, stream>>>(e, ebf, esq, out);
    vq_main<<<NROWS / BM, 256, 0, stream>>>(x, ebf, esq, out);
}

// Round 2
// 846.717 us; speedup vs baseline: 1.6540x; 1.6540x over previous
//
#include <hip/hip_runtime.h>
#include <hip/hip_bf16.h>

// VQ-VAE forward loss on MI355X.
// loss = 2.25 * mean((emb[argmin] - x)^2)
//      = 2.25/(N*D) * [ sum(x^2) + sum_n min_k(||e_k||^2 - 2 x_n.e_k) ]
// GEMM part (x . e_k) in bf16 MFMA 16x16x32; ||x||^2, ||e||^2 exact fp32.
//
// R2: latency fix. 8 waves/block (512 thr), 64 codes/wave (single group ->
// no rmin carry), __launch_bounds__(512,4) to force VGPR<=128 -> 4 waves/SIMD,
// explicit 2-deep register double-buffer of B-fragments across dk.

#define NROWS (64 * 4096)   // 262144
#define DDIM  480
#define KCODES 512
#define BM    64            // rows per block
#define LDSS  488           // padded LDS row stride (bf16 elems); 976 B
#define NT    512           // threads per block (8 waves)

typedef __bf16 bf16x8 __attribute__((ext_vector_type(8)));
typedef float  f32x4  __attribute__((ext_vector_type(4)));

__device__ __forceinline__ ushort f2bf(float v) {
    union { float f; unsigned u; } c; c.f = v;
    unsigned u = c.u;
    u += 0x7fffu + ((u >> 16) & 1u);
    return (ushort)(u >> 16);
}

// Convert codebook to bf16 in ws, compute ||e_k||^2 (fp32 exact), zero d_out.
__global__ void vq_setup(const float* __restrict__ e, ushort* __restrict__ ebf,
                         float* __restrict__ esq, float* __restrict__ out) {
    const int k = blockIdx.x;   // one code row per block (1 wave)
    const int t = threadIdx.x;
    if (k == 0 && t == 0) out[0] = 0.0f;
    float s = 0.0f;
    for (int d = t; d < DDIM; d += 64) {
        float v = e[k * DDIM + d];
        s += v * v;
        ebf[k * DDIM + d] = f2bf(v);
    }
    #pragma unroll
    for (int m = 32; m >= 1; m >>= 1) s += __shfl_xor(s, m, 64);
    if (t == 0) esq[k] = s;
}

__global__ __launch_bounds__(NT, 4) void vq_main(const float* __restrict__ x,
        const ushort* __restrict__ ebf, const float* __restrict__ esq,
        float* __restrict__ out) {
    __shared__ ushort xs[BM * LDSS];   // 62464 B
    __shared__ float red[8 * BM];      // per-wave per-row mins
    __shared__ float redw[8];

    const int t    = threadIdx.x;
    const int wave = t >> 6;
    const int lane = t & 63;
    const int lrow = lane & 15;   // MFMA row/col lane index
    const int quad = lane >> 4;

    // ---- stage X tile (fp32 -> bf16 LDS), accumulate exact sum(x^2) ----
    const float4* xg = (const float4*)(x + (size_t)blockIdx.x * (BM * DDIM));
    float xsq = 0.0f;
    #pragma unroll
    for (int i = 0; i < 15; ++i) {        // 64*480/4 = 7680 float4 / 512 thr
        int f = i * NT + t;
        float4 v = xg[f];
        xsq += v.x * v.x + v.y * v.y + v.z * v.z + v.w * v.w;
        int row = f / 120;                 // 120 float4 per row
        int col = f - row * 120;
        ushort4 b;
        b.x = f2bf(v.x); b.y = f2bf(v.y); b.z = f2bf(v.z); b.w = f2bf(v.w);
        *(ushort4*)(&xs[row * LDSS + col * 4]) = b;
    }
    __syncthreads();

    // ---- each wave: 64 rows x its 64-code slice, one pass over D ----
    const int code0 = wave * 64;
    // B fragment base: lane (lrow,quad) reads code (code0 + c*16 + lrow),
    // elems dk*32 + quad*8 .. +8
    const ushort* bptr = ebf + (size_t)(code0 + lrow) * DDIM + quad * 8;

    f32x4 acc[4][4];                       // [coltile][rowtile]
    #pragma unroll
    for (int c = 0; c < 4; ++c)
        #pragma unroll
        for (int r = 0; r < 4; ++r) acc[c][r] = (f32x4){0.f, 0.f, 0.f, 0.f};

    bf16x8 Bb[2][4];                       // double-buffered B fragments
    #pragma unroll
    for (int c = 0; c < 4; ++c)
        Bb[0][c] = *(const bf16x8*)(bptr + (size_t)c * 16 * DDIM);

    #pragma unroll
    for (int dk = 0; dk < 15; ++dk) {      // D = 15 * 32
        const int cur = dk & 1, nxt = cur ^ 1;
        if (dk < 14) {
            #pragma unroll
            for (int c = 0; c < 4; ++c)
                Bb[nxt][c] = *(const bf16x8*)(bptr + (size_t)c * 16 * DDIM + (dk + 1) * 32);
        }
        #pragma unroll
        for (int r = 0; r < 4; ++r) {
            bf16x8 A = *(const bf16x8*)(&xs[(r * 16 + lrow) * LDSS + dk * 32 + quad * 8]);
            #pragma unroll
            for (int c = 0; c < 4; ++c)
                acc[c][r] = __builtin_amdgcn_mfma_f32_16x16x32_bf16(A, Bb[cur][c], acc[c][r], 0, 0, 0);
        }
    }

    // ---- fold: min_k (esq[k] - 2*dot); acc[c][r][j] is (row=quad*4+j, col=lrow)
    float rmin[4][4];
    #pragma unroll
    for (int r = 0; r < 4; ++r)
        #pragma unroll
        for (int j = 0; j < 4; ++j) rmin[r][j] = 1e30f;
    #pragma unroll
    for (int c = 0; c < 4; ++c) {
        float es = esq[code0 + c * 16 + lrow];
        #pragma unroll
        for (int r = 0; r < 4; ++r)
            #pragma unroll
            for (int j = 0; j < 4; ++j)
                rmin[r][j] = fminf(rmin[r][j], es - 2.0f * acc[c][r][j]);
    }

    // ---- cross-lane min over the 16 col lanes (bits 0..3, stays in quad) ----
    #pragma unroll
    for (int r = 0; r < 4; ++r)
        #pragma unroll
        for (int j = 0; j < 4; ++j) {
            float v = rmin[r][j];
            v = fminf(v, __shfl_xor(v, 1, 64));
            v = fminf(v, __shfl_xor(v, 2, 64));
            v = fminf(v, __shfl_xor(v, 4, 64));
            v = fminf(v, __shfl_xor(v, 8, 64));
            if (lrow == 0) red[wave * 64 + r * 16 + quad * 4 + j] = v;
        }
    __syncthreads();

    // ---- combine: min across 8 waves per row, + sum(x^2), block reduce ----
    float val = xsq;
    if (t < 64) {
        float m0 = fminf(red[t],       red[64 + t]);
        float m1 = fminf(red[128 + t], red[192 + t]);
        float m2 = fminf(red[256 + t], red[320 + t]);
        float m3 = fminf(red[384 + t], red[448 + t]);
        val += fminf(fminf(m0, m1), fminf(m2, m3));
    }
    #pragma unroll
    for (int m = 32; m >= 1; m >>= 1) val += __shfl_xor(val, m, 64);
    if (lane == 0) redw[wave] = val;
    __syncthreads();
    if (t == 0) {
        const float SCALE = 2.25f / ((float)NROWS * (float)DDIM);
        float s = 0.f;
        #pragma unroll
        for (int w = 0; w < 8; ++w) s += redw[w];
        atomicAdd(out, s * SCALE);
    }
}

extern "C" void kernel_launch(void* const* d_in, const int* in_sizes, int n_in,
                              void* d_out, int out_size, void* d_ws, size_t ws_size,
                              hipStream_t stream) {
    (void)in_sizes; (void)n_in; (void)out_size; (void)ws_size;
    const float* x = (const float*)d_in[0];   // [262144, 480] fp32
    const float* e = (const float*)d_in[1];   // [512, 480] fp32
    float* out = (float*)d_out;               // scalar fp32
    ushort* ebf = (ushort*)d_ws;                              // 512*480*2 = 491520 B
    float*  esq = (float*)((char*)d_ws + KCODES * DDIM * 2);  // 512*4 B

    vq_setup<<<KCODES, 64, 0, stream>>>(e, ebf, esq, out);
    vq_main<<<NROWS / BM, NT, 0, stream>>>(x, ebf, esq, out);
}